// Round 1
// baseline (275.140 us; speedup 1.0000x reference)
//
#include <hip/hip_runtime.h>
#include <math.h>

// Problem constants (match reference file).
#define BATCH 256
#define VOCAB 128000
#define HIST  2048
#define EPS_T 1e-5f

#define BLOCK 1024
#define NWAVES (BLOCK / 64)
#define MASK_WORDS (VOCAB / 32)   // 4000 words = 16 KB LDS bitmask

__global__ __launch_bounds__(BLOCK) void sampler_kernel(
    const float* __restrict__ logits,      // [B, V]
    const int*   __restrict__ token_ids,   // [B, L]
    const float* __restrict__ penalties,   // [B]
    const float* __restrict__ temps,       // [B]
    const float* __restrict__ gumbel,      // [B, V]
    int*         __restrict__ out)         // [B]
{
    __shared__ unsigned int mask[MASK_WORDS];
    __shared__ float wval[NWAVES];
    __shared__ int   widx[NWAVES];

    const int b   = blockIdx.x;
    const int tid = threadIdx.x;

    // --- build presence bitmask in LDS ---
    for (int i = tid; i < MASK_WORDS; i += BLOCK) mask[i] = 0u;
    __syncthreads();

    const int* row_tok = token_ids + (size_t)b * HIST;
    for (int i = tid; i < HIST; i += BLOCK) {
        int t = row_tok[i];
        atomicOr(&mask[t >> 5], 1u << (t & 31));
    }
    __syncthreads();

    const float pen    = penalties[b];
    const float temp   = temps[b];
    const bool  greedy = (temp < EPS_T);

    float best  = -INFINITY;
    int   besti = 0x7fffffff;

    const float4* lg = (const float4*)(logits + (size_t)b * VOCAB);
    const float4* gm = (const float4*)(gumbel + (size_t)b * VOCAB);
    const int nvec = VOCAB / 4;   // 32000

    if (greedy) {
        // argmax over penalized logits; gumbel stream never touched.
        for (int i = tid; i < nvec; i += BLOCK) {
            float4 l = lg[i];
            const int v = i * 4;
            const unsigned w = mask[v >> 5];
            const int sh = v & 31;
            float lv[4] = {l.x, l.y, l.z, l.w};
            #pragma unroll
            for (int j = 0; j < 4; j++) {
                float present = (float)((w >> (sh + j)) & 1u);
                // pen*present is exact (present in {0,1}) -> bitwise == numpy
                float p = lv[j] - pen * present;
                int idx = v + j;
                if (p > best || (p == best && idx < besti)) { best = p; besti = idx; }
            }
        }
    } else {
        for (int i = tid; i < nvec; i += BLOCK) {
            float4 l = lg[i];
            float4 g = gm[i];
            const int v = i * 4;
            const unsigned w = mask[v >> 5];
            const int sh = v & 31;
            float lv[4] = {l.x, l.y, l.z, l.w};
            float gv[4] = {g.x, g.y, g.z, g.w};
            #pragma unroll
            for (int j = 0; j < 4; j++) {
                float present = (float)((w >> (sh + j)) & 1u);
                float p = lv[j] - pen * present;
                // same op order as reference: (p / t) + gumbel, IEEE div
                float s = p / temp + gv[j];
                int idx = v + j;
                if (s > best || (s == best && idx < besti)) { best = s; besti = idx; }
            }
        }
    }

    // --- wave-level argmax reduction (64 lanes), first-index tie-break ---
    #pragma unroll
    for (int off = 32; off > 0; off >>= 1) {
        float ov = __shfl_down(best, off, 64);
        int   oi = __shfl_down(besti, off, 64);
        if (ov > best || (ov == best && oi < besti)) { best = ov; besti = oi; }
    }

    const int wave = tid >> 6;
    const int lane = tid & 63;
    if (lane == 0) { wval[wave] = best; widx[wave] = besti; }
    __syncthreads();

    if (tid == 0) {
        #pragma unroll
        for (int wv = 1; wv < NWAVES; wv++) {
            if (wval[wv] > best || (wval[wv] == best && widx[wv] < besti)) {
                best = wval[wv]; besti = widx[wv];
            }
        }
        out[b] = besti;
    }
}

extern "C" void kernel_launch(void* const* d_in, const int* in_sizes, int n_in,
                              void* d_out, int out_size, void* d_ws, size_t ws_size,
                              hipStream_t stream) {
    const float* logits    = (const float*)d_in[0];
    const int*   token_ids = (const int*)d_in[1];
    const float* penalties = (const float*)d_in[2];
    const float* temps     = (const float*)d_in[3];
    const float* gumbel    = (const float*)d_in[4];
    int* out = (int*)d_out;

    sampler_kernel<<<BATCH, BLOCK, 0, stream>>>(logits, token_ids, penalties,
                                                temps, gumbel, out);
}

// Round 2
// 272.549 us; speedup vs baseline: 1.0095x; 1.0095x over previous
//
#include <hip/hip_runtime.h>
#include <math.h>

// Problem constants (match reference file).
#define BATCH 256
#define VOCAB 128000
#define HIST  2048
#define EPS_T 1e-5f

#define BLOCK 1024
#define NWAVES (BLOCK / 64)

#define SEGS 4                       // vocab segments per row
#define SEG_ELEMS (VOCAB / SEGS)     // 32000
#define SEG_VEC   (SEG_ELEMS / 4)    // 8000 float4s
#define SEG_WORDS (SEG_ELEMS / 32)   // 1000 mask words = 4 KB LDS

__device__ __forceinline__ void upd(float s, int idx, float& best, int& besti) {
    if (s > best || (s == best && idx < besti)) { best = s; besti = idx; }
}

__global__ __launch_bounds__(BLOCK) void sampler_partial_kernel(
    const float* __restrict__ logits,      // [B, V]
    const int*   __restrict__ token_ids,   // [B, L]
    const float* __restrict__ penalties,   // [B]
    const float* __restrict__ temps,       // [B]
    const float* __restrict__ gumbel,      // [B, V]
    float*       __restrict__ pvals,       // [B*SEGS] partial max values
    int*         __restrict__ pidxs)       // [B*SEGS] partial argmax (absolute)
{
    __shared__ unsigned int smask[SEG_WORDS];
    __shared__ float wval[NWAVES];
    __shared__ int   widx[NWAVES];

    const int blk = blockIdx.x;
    const int b   = blk >> 2;          // row
    const int seg = blk & 3;           // vocab segment
    const int tid = threadIdx.x;

    // --- build presence bitmask for THIS segment only ---
    if (tid < SEG_WORDS) smask[tid] = 0u;
    __syncthreads();

    const int tok_lo = seg * SEG_ELEMS;
    const int tok_hi = tok_lo + SEG_ELEMS;
    const int* row_tok = token_ids + (size_t)b * HIST;
    for (int i = tid; i < HIST; i += BLOCK) {
        int t = row_tok[i];
        if (t >= tok_lo && t < tok_hi)
            atomicOr(&smask[(t - tok_lo) >> 5], 1u << (t & 31));
    }
    __syncthreads();

    const float pen    = penalties[b];
    const float temp   = temps[b];
    const bool  greedy = (temp < EPS_T);

    float best  = -INFINITY;
    int   besti = 0x7fffffff;

    // float4 pointers, offset to this segment
    const float4* lg = (const float4*)(logits + (size_t)b * VOCAB) + (size_t)seg * SEG_VEC;
    const float4* gm = (const float4*)(gumbel + (size_t)b * VOCAB) + (size_t)seg * SEG_VEC;
    const int abs_base = seg * SEG_ELEMS;   // absolute element index of local 0

    if (greedy) {
        int iv = tid;
        // unroll x4: issue 4 independent float4 loads before consuming
        for (; iv + 3 * BLOCK < SEG_VEC; iv += 4 * BLOCK) {
            float4 l[4];
            #pragma unroll
            for (int k = 0; k < 4; k++) l[k] = lg[iv + k * BLOCK];
            #pragma unroll
            for (int k = 0; k < 4; k++) {
                const int lv = iv + k * BLOCK;        // local vec index
                const unsigned w = smask[lv >> 3];
                const int sh = (lv * 4) & 31;
                float e[4] = {l[k].x, l[k].y, l[k].z, l[k].w};
                #pragma unroll
                for (int j = 0; j < 4; j++) {
                    float present = (float)((w >> (sh + j)) & 1u);
                    float p = e[j] - pen * present;   // exact: present in {0,1}
                    upd(p, abs_base + lv * 4 + j, best, besti);
                }
            }
        }
        for (; iv < SEG_VEC; iv += BLOCK) {
            float4 l = lg[iv];
            const unsigned w = smask[iv >> 3];
            const int sh = (iv * 4) & 31;
            float e[4] = {l.x, l.y, l.z, l.w};
            #pragma unroll
            for (int j = 0; j < 4; j++) {
                float present = (float)((w >> (sh + j)) & 1u);
                float p = e[j] - pen * present;
                upd(p, abs_base + iv * 4 + j, best, besti);
            }
        }
    } else {
        int iv = tid;
        for (; iv + 3 * BLOCK < SEG_VEC; iv += 4 * BLOCK) {
            float4 l[4], g[4];
            #pragma unroll
            for (int k = 0; k < 4; k++) l[k] = lg[iv + k * BLOCK];
            #pragma unroll
            for (int k = 0; k < 4; k++) g[k] = gm[iv + k * BLOCK];
            #pragma unroll
            for (int k = 0; k < 4; k++) {
                const int lv = iv + k * BLOCK;
                const unsigned w = smask[lv >> 3];
                const int sh = (lv * 4) & 31;
                float e[4] = {l[k].x, l[k].y, l[k].z, l[k].w};
                float gv[4] = {g[k].x, g[k].y, g[k].z, g[k].w};
                #pragma unroll
                for (int j = 0; j < 4; j++) {
                    float present = (float)((w >> (sh + j)) & 1u);
                    float p = e[j] - pen * present;
                    float s = p / temp + gv[j];       // reference op order
                    upd(s, abs_base + lv * 4 + j, best, besti);
                }
            }
        }
        for (; iv < SEG_VEC; iv += BLOCK) {
            float4 l = lg[iv];
            float4 g = gm[iv];
            const unsigned w = smask[iv >> 3];
            const int sh = (iv * 4) & 31;
            float e[4] = {l.x, l.y, l.z, l.w};
            float gv[4] = {g.x, g.y, g.z, g.w};
            #pragma unroll
            for (int j = 0; j < 4; j++) {
                float present = (float)((w >> (sh + j)) & 1u);
                float p = e[j] - pen * present;
                float s = p / temp + gv[j];
                upd(s, abs_base + iv * 4 + j, best, besti);
            }
        }
    }

    // --- wave-level argmax reduction (64 lanes), first-index tie-break ---
    #pragma unroll
    for (int off = 32; off > 0; off >>= 1) {
        float ov = __shfl_down(best, off, 64);
        int   oi = __shfl_down(besti, off, 64);
        if (ov > best || (ov == best && oi < besti)) { best = ov; besti = oi; }
    }

    const int wave = tid >> 6;
    const int lane = tid & 63;
    if (lane == 0) { wval[wave] = best; widx[wave] = besti; }
    __syncthreads();

    if (tid == 0) {
        #pragma unroll
        for (int wv = 1; wv < NWAVES; wv++) {
            if (wval[wv] > best || (wval[wv] == best && widx[wv] < besti)) {
                best = wval[wv]; besti = widx[wv];
            }
        }
        pvals[b * SEGS + seg] = best;
        pidxs[b * SEGS + seg] = besti;
    }
}

__global__ void sampler_reduce_kernel(const float* __restrict__ pvals,
                                      const int*   __restrict__ pidxs,
                                      int*         __restrict__ out)
{
    const int b = threadIdx.x;   // 256 threads, one per row
    float best  = pvals[b * SEGS];
    int   besti = pidxs[b * SEGS];
    #pragma unroll
    for (int s = 1; s < SEGS; s++) {
        float v = pvals[b * SEGS + s];
        // strictly greater wins: lower segment = lower indices = numpy tie-break
        if (v > best) { best = v; besti = pidxs[b * SEGS + s]; }
    }
    out[b] = besti;
}

extern "C" void kernel_launch(void* const* d_in, const int* in_sizes, int n_in,
                              void* d_out, int out_size, void* d_ws, size_t ws_size,
                              hipStream_t stream) {
    const float* logits    = (const float*)d_in[0];
    const int*   token_ids = (const int*)d_in[1];
    const float* penalties = (const float*)d_in[2];
    const float* temps     = (const float*)d_in[3];
    const float* gumbel    = (const float*)d_in[4];
    int* out = (int*)d_out;

    float* pvals = (float*)d_ws;
    int*   pidxs = (int*)((float*)d_ws + BATCH * SEGS);

    sampler_partial_kernel<<<BATCH * SEGS, BLOCK, 0, stream>>>(
        logits, token_ids, penalties, temps, gumbel, pvals, pidxs);
    sampler_reduce_kernel<<<1, BATCH, 0, stream>>>(pvals, pidxs, out);
}